// Round 2
// baseline (89665.814 us; speedup 1.0000x reference)
//
#include <hip/hip_runtime.h>
#include <math.h>

#define BB 128
#define SS 512
#define HH 512
#define VV 30
#define TT 64

__device__ __forceinline__ float sigm(float x) { return 1.f / (1.f + expf(-x)); }
__device__ __forceinline__ float dot4(float4 a, float4 b) {
  return a.x * b.x + a.y * b.y + a.z * b.z + a.w * b.w;
}

// =====================================================================
// Encoder phase p (software-pipelined across the two GRU layers):
//   blocks 0..255  : layer0 @ time p   (reads AFc = a_{p-1}, writes AFn = a_p)
//   blocks 256..511: layer1 @ time p-1 (reads AFc = a_{p-1}, CFc = c_{p-2},
//                                       writes CFn = c_{p-1} and out_enc)
// One thread per (m, c) output element; f32 dot products, float4 loads.
// =====================================================================
__global__ __launch_bounds__(256) void enc_phase(
    int p, const float* __restrict__ x,
    const float* __restrict__ Wih0, const float* __restrict__ Whh0,
    const float* __restrict__ bih0, const float* __restrict__ bhh0,
    const float* __restrict__ Wih1, const float* __restrict__ Whh1,
    const float* __restrict__ bih1, const float* __restrict__ bhh1,
    const float* __restrict__ AFc, float* __restrict__ AFn,
    const float* __restrict__ CFc, float* __restrict__ CFn,
    float* __restrict__ oe)
{
  const int bx = blockIdx.x, t = threadIdx.x;
  if (bx < 256) {                       // ---- layer 0, time p ----
    if (p >= SS) return;
    const int m = ((bx >> 5) << 4) | (t >> 4);
    const int c = ((bx & 31) << 4) | (t & 15);
    const float4* a  = (const float4*)(AFc + (size_t)m * HH);
    const float4* wr = (const float4*)(Whh0 + (size_t)c * HH);
    const float4* wz = (const float4*)(Whh0 + (size_t)(HH + c) * HH);
    const float4* wn = (const float4*)(Whh0 + (size_t)(2 * HH + c) * HH);
    float hr = 0.f, hz = 0.f, hn = 0.f;
#pragma unroll 4
    for (int k = 0; k < HH / 4; ++k) {
      float4 av = a[k];
      hr += dot4(av, wr[k]);
      hz += dot4(av, wz[k]);
      hn += dot4(av, wn[k]);
    }
    const float x0 = x[((size_t)m * SS + p) * 2];
    const float x1 = x[((size_t)m * SS + p) * 2 + 1];
    float ir  = bih0[c]          + x0 * Wih0[(size_t)c * 2]              + x1 * Wih0[(size_t)c * 2 + 1];
    float iz  = bih0[HH + c]     + x0 * Wih0[(size_t)(HH + c) * 2]       + x1 * Wih0[(size_t)(HH + c) * 2 + 1];
    float inn = bih0[2*HH + c]   + x0 * Wih0[(size_t)(2 * HH + c) * 2]   + x1 * Wih0[(size_t)(2 * HH + c) * 2 + 1];
    hr += bhh0[c]; hz += bhh0[HH + c]; hn += bhh0[2 * HH + c];
    float r = sigm(ir + hr), z = sigm(iz + hz);
    float n = tanhf(inn + r * hn);
    float hp = AFc[(size_t)m * HH + c];
    AFn[(size_t)m * HH + c] = (1.f - z) * n + z * hp;
  } else {                              // ---- layer 1, time p-1 ----
    if (p == 0) return;
    const int b2 = bx - 256;
    const int m = ((b2 >> 5) << 4) | (t >> 4);
    const int c = ((b2 & 31) << 4) | (t & 15);
    const float4* a1  = (const float4*)(AFc + (size_t)m * HH);
    const float4* a2  = (const float4*)(CFc + (size_t)m * HH);
    const float4* uir = (const float4*)(Wih1 + (size_t)c * HH);
    const float4* uiz = (const float4*)(Wih1 + (size_t)(HH + c) * HH);
    const float4* uin = (const float4*)(Wih1 + (size_t)(2 * HH + c) * HH);
    const float4* uhr = (const float4*)(Whh1 + (size_t)c * HH);
    const float4* uhz = (const float4*)(Whh1 + (size_t)(HH + c) * HH);
    const float4* uhn = (const float4*)(Whh1 + (size_t)(2 * HH + c) * HH);
    float ir = 0.f, iz = 0.f, inn = 0.f, hr = 0.f, hz = 0.f, hn = 0.f;
#pragma unroll 2
    for (int k = 0; k < HH / 4; ++k) {
      float4 v1 = a1[k], v2 = a2[k];
      ir  += dot4(v1, uir[k]); iz += dot4(v1, uiz[k]); inn += dot4(v1, uin[k]);
      hr  += dot4(v2, uhr[k]); hz += dot4(v2, uhz[k]); hn  += dot4(v2, uhn[k]);
    }
    ir += bih1[c]; iz += bih1[HH + c]; inn += bih1[2 * HH + c];
    hr += bhh1[c]; hz += bhh1[HH + c]; hn  += bhh1[2 * HH + c];
    float r = sigm(ir + hr), z = sigm(iz + hz);
    float n = tanhf(inn + r * hn);
    float hp = CFc[(size_t)m * HH + c];
    float val = (1.f - z) * n + z * hp;
    CFn[(size_t)m * HH + c] = val;
    oe[((size_t)m * SS + (p - 1)) * HH + c] = val;
  }
}

// Decoder GRU cell: one thread per (m, c); A1 row optionally gathered via tok.
__global__ __launch_bounds__(256) void dec_gru(
    const float* __restrict__ A1, const int* __restrict__ gather,
    const float* __restrict__ Hprev,
    const float* __restrict__ Wih, const float* __restrict__ Whh,
    const float* __restrict__ bih, const float* __restrict__ bhh,
    float* __restrict__ Hnew)
{
  const int bx = blockIdx.x, t = threadIdx.x;
  const int m = ((bx >> 5) << 4) | (t >> 4);
  const int c = ((bx & 31) << 4) | (t & 15);
  const float* a1row = gather ? (A1 + (size_t)gather[m] * HH)
                              : (A1 + (size_t)m * HH);
  const float4* a1  = (const float4*)a1row;
  const float4* a2  = (const float4*)(Hprev + (size_t)m * HH);
  const float4* uir = (const float4*)(Wih + (size_t)c * HH);
  const float4* uiz = (const float4*)(Wih + (size_t)(HH + c) * HH);
  const float4* uin = (const float4*)(Wih + (size_t)(2 * HH + c) * HH);
  const float4* uhr = (const float4*)(Whh + (size_t)c * HH);
  const float4* uhz = (const float4*)(Whh + (size_t)(HH + c) * HH);
  const float4* uhn = (const float4*)(Whh + (size_t)(2 * HH + c) * HH);
  float ir = 0.f, iz = 0.f, inn = 0.f, hr = 0.f, hz = 0.f, hn = 0.f;
#pragma unroll 2
  for (int k = 0; k < HH / 4; ++k) {
    float4 v1 = a1[k], v2 = a2[k];
    ir += dot4(v1, uir[k]); iz += dot4(v1, uiz[k]); inn += dot4(v1, uin[k]);
    hr += dot4(v2, uhr[k]); hz += dot4(v2, uhz[k]); hn  += dot4(v2, uhn[k]);
  }
  ir += bih[c]; iz += bih[HH + c]; inn += bih[2 * HH + c];
  hr += bhh[c]; hz += bhh[HH + c]; hn  += bhh[2 * HH + c];
  float r = sigm(ir + hr), z = sigm(iz + hz);
  float n = tanhf(inn + r * hn);
  float hp = Hprev[(size_t)m * HH + c];
  Hnew[(size_t)m * HH + c] = (1.f - z) * n + z * hp;
}

// sim[s][b] = dot(out_enc[b,s,:], n1[b,:]); one wave per 16 s-rows.
__global__ __launch_bounds__(256) void sim_kernel(
    const float* __restrict__ n1f, const float* __restrict__ oe,
    float* __restrict__ simt)
{
  const int b = blockIdx.x >> 3, sc = blockIdx.x & 7;
  const int wave = threadIdx.x >> 6, lane = threadIdx.x & 63;
  const float4* xp = (const float4*)(n1f + (size_t)b * HH);
  float4 xa = xp[lane * 2], xb = xp[lane * 2 + 1];
  int s0 = sc * 64 + wave * 16;
  for (int i = 0; i < 16; ++i) {
    int s = s0 + i;
    const float4* op = (const float4*)(oe + ((size_t)b * SS + s) * HH);
    float acc = dot4(xa, op[lane * 2]) + dot4(xb, op[lane * 2 + 1]);
    for (int off = 32; off; off >>= 1) acc += __shfl_down(acc, off);
    if (lane == 0) simt[(size_t)s * BB + b] = acc;
  }
}

// Fused: softmax over BATCH (the reference's dim=0 quirk) -> attention ->
// logits -> argmax feedback. One block per batch element.
__global__ __launch_bounds__(256) void attn_kernel(
    int tstep, const float* __restrict__ simt, const float* __restrict__ n1f,
    const float* __restrict__ oe, const float* __restrict__ fcW,
    const float* __restrict__ fcb, float* __restrict__ dout,
    int* __restrict__ tok)
{
  __shared__ float wsm[SS];
  __shared__ float xv[2 * HH];
  __shared__ float lg[32];
  const int b = blockIdx.x, t = threadIdx.x;

  for (int s = t; s < SS; s += 256) {
    const float* row = simt + (size_t)s * BB;
    float mx = -1e30f;
    for (int i = 0; i < BB; ++i) mx = fmaxf(mx, row[i]);
    float e = 0.f;
    for (int i = 0; i < BB; ++i) e += expf(row[i] - mx);
    wsm[s] = expf(row[b] - mx) / e;
  }
  xv[t]       = n1f[(size_t)b * HH + t];
  xv[t + 256] = n1f[(size_t)b * HH + t + 256];
  __syncthreads();

  {
    float a0 = 0.f, a1 = 0.f;
    const float* base = oe + (size_t)b * SS * HH;
    for (int s = 0; s < SS; ++s) {
      float w = wsm[s];
      a0 += w * base[(size_t)s * HH + t];
      a1 += w * base[(size_t)s * HH + t + 256];
    }
    xv[HH + t]       = a0;
    xv[HH + t + 256] = a1;
  }
  __syncthreads();

  int wave = t >> 6, lane = t & 63;
  for (int v = wave; v < VV; v += 4) {
    const float* wr = fcW + (size_t)v * (2 * HH);
    float acc = 0.f;
#pragma unroll
    for (int i = 0; i < 16; ++i) acc += xv[i * 64 + lane] * wr[i * 64 + lane];
    for (int off = 32; off; off >>= 1) acc += __shfl_down(acc, off);
    if (lane == 0) {
      float lv = acc + fcb[v];
      lg[v] = lv;
      dout[(size_t)b * (TT * VV) + (size_t)tstep * VV + v] = lv;
    }
  }
  __syncthreads();

  if (t == 0) {
    float best = lg[0]; int bi = 0;
    for (int v = 1; v < VV; ++v) if (lg[v] > best) { best = lg[v]; bi = v; }
    tok[b] = bi;
  }
}

__global__ __launch_bounds__(256) void initk(
    float* AF0, float* AF1, float* CF0, float* CF1, int* tok)
{
  int i = blockIdx.x * 256 + threadIdx.x;
  AF0[i] = 0.f; AF1[i] = 0.f; CF0[i] = 0.f; CF1[i] = 0.f;
  if (i < BB) tok[i] = 0;
}

__global__ __launch_bounds__(256) void finalize(
    const float* __restrict__ d0, const float* __restrict__ d1,
    float* __restrict__ oh)
{
  int i = blockIdx.x * 256 + threadIdx.x;
  oh[i]           = d0[i];
  oh[BB * HH + i] = d1[i];
}

extern "C" void kernel_launch(void* const* d_in, const int* in_sizes, int n_in,
                              void* d_out, int out_size, void* d_ws, size_t ws_size,
                              hipStream_t stream) {
  const float* x     = (const float*)d_in[0];
  const float* emb   = (const float*)d_in[1];
  const float* eWih0 = (const float*)d_in[2];
  const float* eWhh0 = (const float*)d_in[3];
  const float* ebih0 = (const float*)d_in[4];
  const float* ebhh0 = (const float*)d_in[5];
  const float* eWih1 = (const float*)d_in[6];
  const float* eWhh1 = (const float*)d_in[7];
  const float* ebih1 = (const float*)d_in[8];
  const float* ebhh1 = (const float*)d_in[9];
  const float* dWih0 = (const float*)d_in[10];
  const float* dWhh0 = (const float*)d_in[11];
  const float* dbih0 = (const float*)d_in[12];
  const float* dbhh0 = (const float*)d_in[13];
  const float* dWih1 = (const float*)d_in[14];
  const float* dWhh1 = (const float*)d_in[15];
  const float* dbih1 = (const float*)d_in[16];
  const float* dbhh1 = (const float*)d_in[17];
  const float* fcW   = (const float*)d_in[18];
  const float* fcb   = (const float*)d_in[19];
  float* dout = (float*)d_out;

  char* wsb = (char*)d_ws;
  float* AF0  = (float*)(wsb + 0);          // 128x512 f32 each
  float* AF1  = (float*)(wsb + 262144);
  float* CF0  = (float*)(wsb + 524288);
  float* CF1  = (float*)(wsb + 786432);
  int*   tok  = (int*)  (wsb + 1048576);
  float* simt = (float*)(wsb + 1052672);    // [S][B] f32
  float* oe   = (float*)(wsb + 1314816);    // out_enc [B][S][H] f32 (128 MiB)

  initk<<<256, 256, 0, stream>>>(AF0, AF1, CF0, CF1, tok);

  const float* afc = AF0; float* afn = AF1;
  const float* cfc = CF0; float* cfn = CF1;
  for (int p = 0; p <= SS; ++p) {
    enc_phase<<<512, 256, 0, stream>>>(p, x,
        eWih0, eWhh0, ebih0, ebhh0, eWih1, eWhh1, ebih1, ebhh1,
        afc, afn, cfc, cfn, oe);
    const float* tc;
    tc = afc; afc = afn; afn = (float*)tc;
    tc = cfc; cfc = cfn; cfn = (float*)tc;
  }
  // a_511 in AF0, c_511 in CF1 (see phase parity trace in session notes)
  const float* d0c = AF0; float* d0n = AF1;
  const float* d1c = CF1; float* d1n = CF0;

  for (int t = 0; t < TT; ++t) {
    dec_gru<<<256, 256, 0, stream>>>(emb, tok, d0c,
                                     dWih0, dWhh0, dbih0, dbhh0, d0n);
    const float* tc = d0c; d0c = d0n; d0n = (float*)tc;
    dec_gru<<<256, 256, 0, stream>>>(d0c, nullptr, d1c,
                                     dWih1, dWhh1, dbih1, dbhh1, d1n);
    tc = d1c; d1c = d1n; d1n = (float*)tc;
    sim_kernel<<<1024, 256, 0, stream>>>(d1c, oe, simt);
    attn_kernel<<<128, 256, 0, stream>>>(t, simt, d1c, oe, fcW, fcb, dout, tok);
  }

  finalize<<<256, 256, 0, stream>>>(d0c, d1c, dout + (size_t)BB * TT * VV);
}

// Round 3
// 27434.641 us; speedup vs baseline: 3.2683x; 3.2683x over previous
//
#include <hip/hip_runtime.h>
#include <math.h>

typedef short  s16x8 __attribute__((ext_vector_type(8)));
typedef float  f32x4 __attribute__((ext_vector_type(4)));
typedef unsigned short u16;

#define MFMA16(a, b, c) __builtin_amdgcn_mfma_f32_16x16x32_bf16((a), (b), (c), 0, 0, 0)

#define BB 128
#define SS 512
#define HH 512
#define VV 30
#define TT 64

__device__ __forceinline__ float b2f(u16 v) {
  union { unsigned int u; float f; } c; c.u = ((unsigned int)v) << 16; return c.f;
}
__device__ __forceinline__ u16 f2b(float f) {
  union { float f; unsigned int u; } c; c.f = f;
  unsigned int r = (c.u + 0x7FFFu + ((c.u >> 16) & 1u)) >> 16;
  return (u16)r;
}
__device__ __forceinline__ float sigm(float x) { return 1.f / (1.f + expf(-x)); }
__device__ __forceinline__ s16x8 ldf(const u16* p) { return *(const s16x8*)p; }

// Split-f32 format: per logical row of K=512, u16 row of 1024: [hi x512 | lo x512].
// hi = bf16(v), lo = bf16(v - hi). GEMM does hi*hi + hi*lo + lo*hi (Markidis).

// =====================================================================
// Dual-input GRU cell (layer-1 / decoder): 64 blocks x 256 thr.
// Block bx: j0=(bx>>1)*16 H-cols, m0=(bx&1)*64; wave covers 16 m-rows.
// 6 gate tiles: 0..2 = A1@Wih rows, 3..5 = A2@Whh rows. Lane-local epilogue.
// MFMA 16x16x32 bf16, B^T convention (weights stored row=out-col, k inner).
// =====================================================================
__device__ __forceinline__ void gru_dual(
    int bx,
    const u16* __restrict__ A1s, const int* __restrict__ gather,
    const u16* __restrict__ A2s,
    const u16* __restrict__ Wihs, const u16* __restrict__ Whhs,
    const float* __restrict__ bih, const float* __restrict__ bhh,
    float* __restrict__ hf, u16* __restrict__ hs_new,
    u16* __restrict__ oe, size_t oe_mstride)
{
  const int tid  = threadIdx.x;
  const int wave = tid >> 6, lane = tid & 63;
  const int lrow = lane & 15, lq = lane >> 4;
  const int j0 = (bx >> 1) * 16;
  const int m0 = (bx & 1) * 64 + wave * 16;

  const u16* a1p;
  if (gather) a1p = A1s + (size_t)gather[m0 + lrow] * 1024 + lq * 8;
  else        a1p = A1s + (size_t)(m0 + lrow) * 1024 + lq * 8;
  const u16* a2p = A2s + (size_t)(m0 + lrow) * 1024 + lq * 8;

  const u16* bp[6];
#pragma unroll
  for (int t = 0; t < 6; ++t) {
    int g = (t < 3) ? t : t - 3;
    const u16* W = (t < 3) ? Wihs : Whhs;
    bp[t] = W + (size_t)(g * HH + j0 + lrow) * 1024 + lq * 8;
  }

  f32x4 acc[6];
#pragma unroll
  for (int t = 0; t < 6; ++t) acc[t] = (f32x4){0.f, 0.f, 0.f, 0.f};

  for (int ks = 0; ks < HH; ks += 32) {
    s16x8 a1h = ldf(a1p), a1l = ldf(a1p + 512); a1p += 32;
    s16x8 a2h = ldf(a2p), a2l = ldf(a2p + 512); a2p += 32;
#pragma unroll
    for (int t = 0; t < 6; ++t) {
      s16x8 bh = ldf(bp[t]), bl = ldf(bp[t] + 512); bp[t] += 32;
      s16x8 ah = (t < 3) ? a1h : a2h;
      s16x8 al = (t < 3) ? a1l : a2l;
      acc[t] = MFMA16(ah, bh, acc[t]);
      acc[t] = MFMA16(ah, bl, acc[t]);
      acc[t] = MFMA16(al, bh, acc[t]);
    }
  }

  const int c = j0 + lrow;
  const float bir = bih[c], biz = bih[HH + c], bin = bih[2 * HH + c];
  const float bhr = bhh[c], bhz = bhh[HH + c], bhn = bhh[2 * HH + c];
#pragma unroll
  for (int r = 0; r < 4; ++r) {
    int m = m0 + lq * 4 + r;
    float ir = acc[0][r] + bir, iz = acc[1][r] + biz, inn = acc[2][r] + bin;
    float hr = acc[3][r] + bhr, hz = acc[4][r] + bhz, hn = acc[5][r] + bhn;
    float rr = sigm(ir + hr);
    float zz = sigm(iz + hz);
    float nn = tanhf(inn + rr * hn);
    float hp = hf[(size_t)m * HH + c];
    float hv = (1.f - zz) * nn + zz * hp;
    hf[(size_t)m * HH + c] = hv;
    u16 hi = f2b(hv);
    hs_new[(size_t)m * 1024 + c]       = hi;
    hs_new[(size_t)m * 1024 + 512 + c] = f2b(hv - b2f(hi));
    if (oe) oe[(size_t)m * oe_mstride + c] = hi;
  }
}

// Encoder layer-0: gh via MFMA (split A = a_{p-1}, split Whh0); gi inline f32
// (K=2, exact). 32 blocks x 256 thr; wave covers 32 m-rows (2 m-tiles).
__device__ __forceinline__ void gru_l0(
    int bx, int p,
    const float* __restrict__ x, const float* __restrict__ Wih0,
    const u16* __restrict__ Whh0s,
    const float* __restrict__ bih0, const float* __restrict__ bhh0,
    const u16* __restrict__ As,
    float* __restrict__ af, u16* __restrict__ as_new)
{
  const int tid  = threadIdx.x;
  const int wave = tid >> 6, lane = tid & 63;
  const int lrow = lane & 15, lq = lane >> 4;
  const int j0 = bx * 16;
  const int mw = wave * 32;

  const u16* ap0 = As + (size_t)(mw + lrow) * 1024 + lq * 8;
  const u16* ap1 = As + (size_t)(mw + 16 + lrow) * 1024 + lq * 8;
  const u16* bp[3];
#pragma unroll
  for (int t = 0; t < 3; ++t)
    bp[t] = Whh0s + (size_t)(t * HH + j0 + lrow) * 1024 + lq * 8;

  f32x4 acc[2][3];
#pragma unroll
  for (int i = 0; i < 2; ++i)
#pragma unroll
    for (int t = 0; t < 3; ++t) acc[i][t] = (f32x4){0.f, 0.f, 0.f, 0.f};

  for (int ks = 0; ks < HH; ks += 32) {
    s16x8 a0h = ldf(ap0), a0l = ldf(ap0 + 512); ap0 += 32;
    s16x8 a1h = ldf(ap1), a1l = ldf(ap1 + 512); ap1 += 32;
#pragma unroll
    for (int t = 0; t < 3; ++t) {
      s16x8 bh = ldf(bp[t]), bl = ldf(bp[t] + 512); bp[t] += 32;
      acc[0][t] = MFMA16(a0h, bh, acc[0][t]);
      acc[0][t] = MFMA16(a0h, bl, acc[0][t]);
      acc[0][t] = MFMA16(a0l, bh, acc[0][t]);
      acc[1][t] = MFMA16(a1h, bh, acc[1][t]);
      acc[1][t] = MFMA16(a1h, bl, acc[1][t]);
      acc[1][t] = MFMA16(a1l, bh, acc[1][t]);
    }
  }

  const int c = j0 + lrow;
  const float bir = bih0[c], biz = bih0[HH + c], bin = bih0[2 * HH + c];
  const float bhr = bhh0[c], bhz = bhh0[HH + c], bhn = bhh0[2 * HH + c];
  const float wr0 = Wih0[(size_t)c * 2],            wr1 = Wih0[(size_t)c * 2 + 1];
  const float wz0 = Wih0[(size_t)(HH + c) * 2],     wz1 = Wih0[(size_t)(HH + c) * 2 + 1];
  const float wn0 = Wih0[(size_t)(2 * HH + c) * 2], wn1 = Wih0[(size_t)(2 * HH + c) * 2 + 1];
#pragma unroll
  for (int tm = 0; tm < 2; ++tm) {
#pragma unroll
    for (int r = 0; r < 4; ++r) {
      int m = mw + tm * 16 + lq * 4 + r;
      float x0 = x[((size_t)m * SS + p) * 2];
      float x1 = x[((size_t)m * SS + p) * 2 + 1];
      float ir  = bir + x0 * wr0 + x1 * wr1;
      float iz  = biz + x0 * wz0 + x1 * wz1;
      float inn = bin + x0 * wn0 + x1 * wn1;
      float hr = acc[tm][0][r] + bhr, hz = acc[tm][1][r] + bhz, hn = acc[tm][2][r] + bhn;
      float rr = sigm(ir + hr);
      float zz = sigm(iz + hz);
      float nn = tanhf(inn + rr * hn);
      float hp = af[(size_t)m * HH + c];
      float hv = (1.f - zz) * nn + zz * hp;
      af[(size_t)m * HH + c] = hv;
      u16 hi = f2b(hv);
      as_new[(size_t)m * 1024 + c]       = hi;
      as_new[(size_t)m * 1024 + 512 + c] = f2b(hv - b2f(hi));
    }
  }
}

// Encoder phase p: blocks 0..31 = layer0@t=p (p<S); 32..95 = layer1@t=p-1.
__global__ __launch_bounds__(256) void enc_phase(
    int p,
    const float* __restrict__ x, const float* __restrict__ Wih0,
    const u16* __restrict__ Whh0s,
    const float* __restrict__ bih0, const float* __restrict__ bhh0,
    const u16* __restrict__ Wih1s, const u16* __restrict__ Whh1s,
    const float* __restrict__ bih1, const float* __restrict__ bhh1,
    const u16* abf_cur, u16* abf_new, float* af,
    const u16* cbf_cur, u16* cbf_new, float* cf,
    u16* out_enc)
{
  int bx = blockIdx.x;
  if (bx < 32) {
    if (p >= SS) return;
    gru_l0(bx, p, x, Wih0, Whh0s, bih0, bhh0, abf_cur, af, abf_new);
  } else {
    if (p == 0) return;
    u16* oe = out_enc + (size_t)(p - 1) * HH;
    gru_dual(bx - 32, abf_cur, nullptr, cbf_cur, Wih1s, Whh1s, bih1, bhh1,
             cf, cbf_new, oe, (size_t)SS * HH);
  }
}

__global__ __launch_bounds__(256) void dec_gru(
    const u16* A1s, const int* gather, const u16* A2s,
    const u16* __restrict__ Wihs, const u16* __restrict__ Whhs,
    const float* __restrict__ bih, const float* __restrict__ bhh,
    float* hf, u16* hs_new)
{
  gru_dual(blockIdx.x, A1s, gather, A2s, Wihs, Whhs, bih, bhh, hf, hs_new,
           nullptr, 0);
}

// sim[s][b] = dot(out_enc[b,s,:], n1[b,:]); one wave per 16 s-rows. oe is bf16.
__global__ __launch_bounds__(256) void sim_kernel(
    const float* __restrict__ n1f, const u16* __restrict__ oe,
    float* __restrict__ simt)
{
  const int b = blockIdx.x >> 3, sc = blockIdx.x & 7;
  const int wave = threadIdx.x >> 6, lane = threadIdx.x & 63;
  float xr[8];
  const float* xp = n1f + (size_t)b * HH + lane * 8;
#pragma unroll
  for (int j = 0; j < 8; ++j) xr[j] = xp[j];
  int s0 = sc * 64 + wave * 16;
  for (int i = 0; i < 16; ++i) {
    int s = s0 + i;
    s16x8 ov = *(const s16x8*)(oe + ((size_t)b * SS + s) * HH + lane * 8);
    float acc = 0.f;
#pragma unroll
    for (int j = 0; j < 8; ++j) acc += xr[j] * b2f((u16)ov[j]);
    for (int off = 32; off; off >>= 1) acc += __shfl_down(acc, off);
    if (lane == 0) simt[(size_t)s * BB + b] = acc;
  }
}

// Fused: softmax over BATCH (reference dim=0 quirk) -> attention -> logits ->
// argmax feedback. One block per batch element.
__global__ __launch_bounds__(256) void attn_kernel(
    int tstep, const float* __restrict__ simt, const float* __restrict__ n1f,
    const u16* __restrict__ oe, const float* __restrict__ fcW,
    const float* __restrict__ fcb, float* __restrict__ dout,
    int* __restrict__ tok)
{
  __shared__ float wsm[SS];
  __shared__ float xv[2 * HH];
  __shared__ float lg[32];
  const int b = blockIdx.x, t = threadIdx.x;

  for (int s = t; s < SS; s += 256) {
    const float* row = simt + (size_t)s * BB;
    float mx = -1e30f;
    for (int i = 0; i < BB; ++i) mx = fmaxf(mx, row[i]);
    float e = 0.f;
    for (int i = 0; i < BB; ++i) e += expf(row[i] - mx);
    wsm[s] = expf(row[b] - mx) / e;
  }
  xv[t]       = n1f[(size_t)b * HH + t];
  xv[t + 256] = n1f[(size_t)b * HH + t + 256];
  __syncthreads();

  {
    float a0 = 0.f, a1 = 0.f;
    const u16* base = oe + (size_t)b * SS * HH;
    for (int s = 0; s < SS; ++s) {
      float w = wsm[s];
      a0 += w * b2f(base[(size_t)s * HH + t]);
      a1 += w * b2f(base[(size_t)s * HH + t + 256]);
    }
    xv[HH + t]       = a0;
    xv[HH + t + 256] = a1;
  }
  __syncthreads();

  int wave = t >> 6, lane = t & 63;
  for (int v = wave; v < VV; v += 4) {
    const float* wr = fcW + (size_t)v * (2 * HH);
    float acc = 0.f;
#pragma unroll
    for (int i = 0; i < 16; ++i) acc += xv[i * 64 + lane] * wr[i * 64 + lane];
    for (int off = 32; off; off >>= 1) acc += __shfl_down(acc, off);
    if (lane == 0) {
      float lv = acc + fcb[v];
      lg[v] = lv;
      dout[(size_t)b * (TT * VV) + (size_t)tstep * VV + v] = lv;
    }
  }
  __syncthreads();

  if (t == 0) {
    float best = lg[0]; int bi = 0;
    for (int v = 1; v < VV; ++v) if (lg[v] > best) { best = lg[v]; bi = v; }
    tok[b] = bi;
  }
}

// Split a f32 matrix [rows][512] into [rows][hi x512 | lo x512] u16.
__global__ __launch_bounds__(256) void splitk(
    const float* __restrict__ src, u16* __restrict__ dst, int n)
{
  int i = blockIdx.x * 256 + threadIdx.x;
  if (i >= n) return;
  int r = i >> 9, k = i & 511;
  float v = src[i];
  u16 hi = f2b(v);
  dst[(size_t)r * 1024 + k]       = hi;
  dst[(size_t)r * 1024 + 512 + k] = f2b(v - b2f(hi));
}

__global__ __launch_bounds__(256) void initk(
    float* af, float* cf, u16* b0, u16* b1, u16* b2, u16* b3, int* tok)
{
  int i = blockIdx.x * 256 + threadIdx.x;   // 131072 threads
  b0[i] = 0; b1[i] = 0; b2[i] = 0; b3[i] = 0;
  if (i < BB * HH) { af[i] = 0.f; cf[i] = 0.f; }
  if (i < BB) tok[i] = 0;
}

__global__ __launch_bounds__(256) void finalize(
    const float* __restrict__ d0, const float* __restrict__ d1,
    float* __restrict__ oh)
{
  int i = blockIdx.x * 256 + threadIdx.x;
  oh[i]           = d0[i];
  oh[BB * HH + i] = d1[i];
}

extern "C" void kernel_launch(void* const* d_in, const int* in_sizes, int n_in,
                              void* d_out, int out_size, void* d_ws, size_t ws_size,
                              hipStream_t stream) {
  const float* x     = (const float*)d_in[0];
  const float* emb   = (const float*)d_in[1];
  const float* eWih0 = (const float*)d_in[2];
  const float* eWhh0 = (const float*)d_in[3];
  const float* ebih0 = (const float*)d_in[4];
  const float* ebhh0 = (const float*)d_in[5];
  const float* eWih1 = (const float*)d_in[6];
  const float* eWhh1 = (const float*)d_in[7];
  const float* ebih1 = (const float*)d_in[8];
  const float* ebhh1 = (const float*)d_in[9];
  const float* dWih0 = (const float*)d_in[10];
  const float* dWhh0 = (const float*)d_in[11];
  const float* dbih0 = (const float*)d_in[12];
  const float* dbhh0 = (const float*)d_in[13];
  const float* dWih1 = (const float*)d_in[14];
  const float* dWhh1 = (const float*)d_in[15];
  const float* dbih1 = (const float*)d_in[16];
  const float* dbhh1 = (const float*)d_in[17];
  const float* fcW   = (const float*)d_in[18];
  const float* fcb   = (const float*)d_in[19];
  float* dout = (float*)d_out;

  char* wsb = (char*)d_ws;
  float* af   = (float*)(wsb + 0);          // 128x512 f32 (a / d0 state, RMW)
  float* cf   = (float*)(wsb + 262144);     // 128x512 f32 (c / d1 state, RMW)
  u16* ABF0   = (u16*)(wsb + 524288);       // split states 128x1024 u16 each
  u16* ABF1   = (u16*)(wsb + 786432);
  u16* CBF0   = (u16*)(wsb + 1048576);
  u16* CBF1   = (u16*)(wsb + 1310720);
  int* tok    = (int*)(wsb + 1572864);
  float* simt = (float*)(wsb + 1573376);    // [S][B] f32, 256 KB
  u16* WeHH0  = (u16*)(wsb + 1835520);      // split weights, 3 MB each
  u16* WeIH1  = (u16*)(wsb + 4981248);
  u16* WeHH1  = (u16*)(wsb + 8126976);
  u16* WdIH0  = (u16*)(wsb + 11272704);
  u16* WdHH0  = (u16*)(wsb + 14418432);
  u16* WdIH1  = (u16*)(wsb + 17564160);
  u16* WdHH1  = (u16*)(wsb + 20709888);
  u16* EMBs   = (u16*)(wsb + 23855616);     // 30x1024 u16
  u16* oe     = (u16*)(wsb + 23917056);     // out_enc bf16 [B][S][H], 64 MiB

  initk<<<512, 256, 0, stream>>>(af, cf, ABF0, ABF1, CBF0, CBF1, tok);

  const int WN = 3 * HH * HH;               // 786432
  splitk<<<(WN + 255) / 256, 256, 0, stream>>>(eWhh0, WeHH0, WN);
  splitk<<<(WN + 255) / 256, 256, 0, stream>>>(eWih1, WeIH1, WN);
  splitk<<<(WN + 255) / 256, 256, 0, stream>>>(eWhh1, WeHH1, WN);
  splitk<<<(WN + 255) / 256, 256, 0, stream>>>(dWih0, WdIH0, WN);
  splitk<<<(WN + 255) / 256, 256, 0, stream>>>(dWhh0, WdHH0, WN);
  splitk<<<(WN + 255) / 256, 256, 0, stream>>>(dWih1, WdIH1, WN);
  splitk<<<(WN + 255) / 256, 256, 0, stream>>>(dWhh1, WdHH1, WN);
  splitk<<<(VV * HH + 255) / 256, 256, 0, stream>>>(emb, EMBs, VV * HH);

  const u16* pa = ABF0; u16* pa_n = ABF1;
  const u16* pc = CBF0; u16* pc_n = CBF1;
  for (int p = 0; p <= SS; ++p) {
    enc_phase<<<96, 256, 0, stream>>>(p, x, eWih0, WeHH0, ebih0, ebhh0,
                                      WeIH1, WeHH1, ebih1, ebhh1,
                                      pa, pa_n, af, pc, pc_n, cf, oe);
    const u16* tp;
    tp = pa; pa = pa_n; pa_n = (u16*)tp;
    tp = pc; pc = pc_n; pc_n = (u16*)tp;
  }
  // a_511 split in ABF0 (written p=511); c_511 split in CBF1 (written p=512)
  const u16* d0c = ABF0; u16* d0n = ABF1;
  const u16* d1c = CBF1; u16* d1n = CBF0;

  for (int t = 0; t < TT; ++t) {
    dec_gru<<<64, 256, 0, stream>>>(EMBs, tok, d0c, WdIH0, WdHH0,
                                    dbih0, dbhh0, af, d0n);
    const u16* tp = d0c; d0c = d0n; d0n = (u16*)tp;
    dec_gru<<<64, 256, 0, stream>>>(d0c, nullptr, d1c, WdIH1, WdHH1,
                                    dbih1, dbhh1, cf, d1n);
    tp = d1c; d1c = d1n; d1n = (u16*)tp;
    sim_kernel<<<1024, 256, 0, stream>>>(cf, oe, simt);
    attn_kernel<<<128, 256, 0, stream>>>(t, simt, cf, oe, fcW, fcb, dout, tok);
  }

  finalize<<<256, 256, 0, stream>>>(af, cf, dout + (size_t)BB * TT * VV);
}